// Round 2
// baseline (74.100 us; speedup 1.0000x reference)
//
#include <hip/hip_runtime.h>

#define BLK 256
#define KJ 4                 // j's per thread -> JLANES = 1024 j's per block
#define JLANES (BLK * KJ)
#define ITILE 64             // i's per block (wave-uniform scalar loop)
#define IB 16                // i-batch for s_load_dwordx16 groups
#define GX (8192 / ITILE)    // 128
#define GY (8192 / JLANES)   // 8
#define NSLOTS (GX * GY)     // 1024 blocks, one 4-dword slot each
#define MAGIC 0x1F2E3D4Cu    // not a repeated-byte pattern: cannot collide with memset poison

__global__ __launch_bounds__(BLK) void svm_fused(
    const float* __restrict__ pred,
    const float2* __restrict__ tg,
    unsigned int* __restrict__ ws,   // NSLOTS * 4 uints
    float* __restrict__ out, int n) {
  const int tid = threadIdx.x;
  const int i0 = blockIdx.x * ITILE;
  const int j0 = blockIdx.y * JLANES;

  // Per-lane j data: loaded once, lives in VGPRs (KJ=4 -> 8 VGPRs).
  float pj[KJ], tj[KJ];
  #pragma unroll
  for (int k = 0; k < KJ; ++k) {
    pj[k] = pred[j0 + tid + k * BLK];
    tj[k] = tg[j0 + tid + k * BLK].x;
  }

  float rank = 0.0f;
  unsigned int cnt = 0u;     // wave-uniform: ballot/popcount path

  // i is wave-uniform: contiguous batches scalarize to s_load_dwordx16;
  // event check is a uniform scalar branch skipping ~half the i's.
  for (int ib = 0; ib < ITILE; ib += IB) {
    float pi[IB], ti[IB], ei[IB];
    #pragma unroll
    for (int u = 0; u < IB; ++u) {
      pi[u] = pred[i0 + ib + u];
      float2 te = tg[i0 + ib + u];
      ti[u] = te.x;
      ei[u] = te.y;
    }
    #pragma unroll
    for (int u = 0; u < IB; ++u) {
      if (ei[u] == 1.0f) {                 // uniform scalar branch
        const float pi1 = pi[u] + 1.0f;
        #pragma unroll
        for (int k = 0; k < KJ; ++k) {
          const bool m = tj[k] > ti[u];    // v_cmp -> mask
          cnt += (unsigned int)__popcll(__ballot(m));  // scalar pipe
          float h = fmaxf(pi1 - pj[k], 0.0f);
          h = m ? h : 0.0f;                // cndmask
          rank = fmaf(h, h, rank);
        }
      }
    }
  }

  // Regression term: counted exactly once (y==0 slice, tid<ITILE).
  float reg = 0.0f;
  if (blockIdx.y == 0 && tid < ITILE) {
    const int i = i0 + tid;
    const float p = pred[i];
    const float2 te = tg[i];
    float d = p - te.x;
    if (te.y == 0.0f) d = fmaxf(d, 0.0f);
    reg = d * d;
  }

  // 64-lane shuffle reduction (rank/reg only; cnt is wave-uniform)
  #pragma unroll
  for (int off = 32; off > 0; off >>= 1) {
    rank += __shfl_down(rank, off);
    reg  += __shfl_down(reg, off);
  }

  __shared__ float sr[BLK / 64];
  __shared__ float sg[BLK / 64];
  __shared__ unsigned int sc[BLK / 64];
  const int wave = tid >> 6;
  const int lane = tid & 63;
  if (lane == 0) { sr[wave] = rank; sg[wave] = reg; sc[wave] = cnt; }
  __syncthreads();

  const int slot = blockIdx.y * GX + blockIdx.x;

  if (tid == 0) {
    const float r = sr[0] + sr[1] + sr[2] + sr[3];
    const float g = sg[0] + sg[1] + sg[2] + sg[3];
    const unsigned int c = sc[0] + sc[1] + sc[2] + sc[3];
    // Publish through L3 (agent scope, sc1): visible across XCDs without
    // relying on L2 writeback ordering. Flag store is RELEASE.
    unsigned int* s = ws + 4 * slot;
    __hip_atomic_store(s + 0, __float_as_uint(r), __ATOMIC_RELAXED, __HIP_MEMORY_SCOPE_AGENT);
    __hip_atomic_store(s + 1, __float_as_uint(g), __ATOMIC_RELAXED, __HIP_MEMORY_SCOPE_AGENT);
    __hip_atomic_store(s + 2, c,                  __ATOMIC_RELAXED, __HIP_MEMORY_SCOPE_AGENT);
    __hip_atomic_store(s + 3, MAGIC,              __ATOMIC_RELEASE, __HIP_MEMORY_SCOPE_AGENT);
  }

  // Aggregator: last slot's block, wave 0 only. Deadlock-free: no other
  // block ever waits on this one; pending blocks can always launch as
  // finished blocks retire.
  if (slot == NSLOTS - 1 && tid < 64) {
    // Spin until all 1024 flags are MAGIC (16 flags per lane).
    bool ready = false;
    while (!ready) {
      bool mine = true;
      #pragma unroll
      for (int q = 0; q < NSLOTS / 64; ++q) {
        const int s = tid + q * 64;
        const unsigned int f = __hip_atomic_load(ws + 4 * s + 3,
                                                 __ATOMIC_ACQUIRE,
                                                 __HIP_MEMORY_SCOPE_AGENT);
        mine &= (f == MAGIC);
      }
      ready = (bool)__all(mine);
    }

    // Same slot->lane assignment and double accumulation order as the old
    // svm_finalize kernel: bit-identical result.
    double r = 0.0, g = 0.0, c = 0.0;
    #pragma unroll
    for (int q = 0; q < NSLOTS / 64; ++q) {
      const int s = tid + q * 64;
      const unsigned int ur = __hip_atomic_load(ws + 4 * s + 0, __ATOMIC_RELAXED, __HIP_MEMORY_SCOPE_AGENT);
      const unsigned int ug = __hip_atomic_load(ws + 4 * s + 1, __ATOMIC_RELAXED, __HIP_MEMORY_SCOPE_AGENT);
      const unsigned int uc = __hip_atomic_load(ws + 4 * s + 2, __ATOMIC_RELAXED, __HIP_MEMORY_SCOPE_AGENT);
      r += (double)__uint_as_float(ur);
      g += (double)__uint_as_float(ug);
      c += (double)uc;                 // each term integral & exact
      // Clear the flag so correctness never depends on the harness
      // re-poisoning ws between graph iterations.
      __hip_atomic_store(ws + 4 * s + 3, 0u, __ATOMIC_RELAXED, __HIP_MEMORY_SCOPE_AGENT);
    }
    #pragma unroll
    for (int off = 32; off > 0; off >>= 1) {
      r += __shfl_down(r, off);
      g += __shfl_down(g, off);
      c += __shfl_down(c, off);
    }
    if (tid == 0) {
      const double cd = (c > 0.0 ? c : 1.0);
      out[0] = (float)(0.5 * r / cd + 0.5 * g / (double)n);
    }
  }
}

extern "C" void kernel_launch(void* const* d_in, const int* in_sizes, int n_in,
                              void* d_out, int out_size, void* d_ws, size_t ws_size,
                              hipStream_t stream) {
  const float* pred = (const float*)d_in[0];
  const float2* tg = (const float2*)d_in[1];
  float* out = (float*)d_out;
  const int n = in_sizes[0];  // 8192

  unsigned int* ws = (unsigned int*)d_ws;

  svm_fused<<<dim3(GX, GY), BLK, 0, stream>>>(pred, tg, ws, out, n);
}

// Round 3
// 67.858 us; speedup vs baseline: 1.0920x; 1.0920x over previous
//
#include <hip/hip_runtime.h>

#define BLK 256
#define KJ 4                 // j's per thread -> JLANES = 1024 j's per block
#define JLANES (BLK * KJ)
#define ITILE 64             // i's per block (wave-uniform scalar loop)
#define IB 16                // i-batch for s_load_dwordx16 groups
#define GX (8192 / ITILE)    // 128
#define GY (8192 / JLANES)   // 8
#define NSLOTS (GX * GY)     // 1024 blocks, one float4 slot each

__global__ __launch_bounds__(BLK) void svm_partial(
    const float* __restrict__ pred,
    const float2* __restrict__ tg,
    float4* __restrict__ ws_slots) {
  const int tid = threadIdx.x;
  const int i0 = blockIdx.x * ITILE;
  const int j0 = blockIdx.y * JLANES;

  // Per-lane j data: loaded once, lives in VGPRs (KJ=4 -> 8 VGPRs).
  float pj[KJ], tj[KJ];
  #pragma unroll
  for (int k = 0; k < KJ; ++k) {
    pj[k] = pred[j0 + tid + k * BLK];
    tj[k] = tg[j0 + tid + k * BLK].x;
  }

  float rank = 0.0f;
  unsigned int cnt = 0u;     // wave-uniform: ballot/popcount path

  // i is wave-uniform: contiguous batches scalarize to s_load_dwordx16;
  // event check is a uniform scalar branch skipping ~half the i's.
  for (int ib = 0; ib < ITILE; ib += IB) {
    float pi[IB], ti[IB], ei[IB];
    #pragma unroll
    for (int u = 0; u < IB; ++u) {
      pi[u] = pred[i0 + ib + u];
      float2 te = tg[i0 + ib + u];
      ti[u] = te.x;
      ei[u] = te.y;
    }
    #pragma unroll
    for (int u = 0; u < IB; ++u) {
      if (ei[u] == 1.0f) {                 // uniform scalar branch
        const float pi1 = pi[u] + 1.0f;
        #pragma unroll
        for (int k = 0; k < KJ; ++k) {
          const bool m = tj[k] > ti[u];    // v_cmp -> mask
          cnt += (unsigned int)__popcll(__ballot(m));  // scalar pipe
          float h = fmaxf(pi1 - pj[k], 0.0f);
          h = m ? h : 0.0f;                // cndmask
          rank = fmaf(h, h, rank);
        }
      }
    }
  }

  // Regression term: counted exactly once (y==0 slice, tid<ITILE).
  float reg = 0.0f;
  if (blockIdx.y == 0 && tid < ITILE) {
    const int i = i0 + tid;
    const float p = pred[i];
    const float2 te = tg[i];
    float d = p - te.x;
    if (te.y == 0.0f) d = fmaxf(d, 0.0f);
    reg = d * d;
  }

  // 64-lane shuffle reduction (rank/reg only; cnt is wave-uniform)
  #pragma unroll
  for (int off = 32; off > 0; off >>= 1) {
    rank += __shfl_down(rank, off);
    reg  += __shfl_down(reg, off);
  }

  __shared__ float sr[BLK / 64];
  __shared__ float sg[BLK / 64];
  __shared__ unsigned int sc[BLK / 64];
  const int wave = tid >> 6;
  const int lane = tid & 63;
  if (lane == 0) { sr[wave] = rank; sg[wave] = reg; sc[wave] = cnt; }
  __syncthreads();

  if (tid == 0) {
    const float r = sr[0] + sr[1] + sr[2] + sr[3];
    const float g = sg[0] + sg[1] + sg[2] + sg[3];
    const unsigned int c = sc[0] + sc[1] + sc[2] + sc[3];
    // c <= ITILE*JLANES = 65536: exactly representable in float.
    const int slot = blockIdx.y * GX + blockIdx.x;
    ws_slots[slot] = make_float4(r, g, (float)c, 0.0f);  // one dwordx4 store
  }
}

// Single wave, no barrier; NSLOTS/64 = 16 dwordx4 loads per lane, pipelined.
__global__ __launch_bounds__(64) void svm_finalize(
    const float4* __restrict__ ws_slots,
    float* __restrict__ out, int n) {
  const int tid = threadIdx.x;
  double r = 0.0, g = 0.0, c = 0.0;
  #pragma unroll
  for (int s = tid; s < NSLOTS; s += 64) {
    const float4 v = ws_slots[s];
    r += (double)v.x;
    g += (double)v.y;
    c += (double)v.z;     // each term integral & exact
  }
  #pragma unroll
  for (int off = 32; off > 0; off >>= 1) {
    r += __shfl_down(r, off);
    g += __shfl_down(g, off);
    c += __shfl_down(c, off);
  }
  if (tid == 0) {
    const double cd = (c > 0.0 ? c : 1.0);
    out[0] = (float)(0.5 * r / cd + 0.5 * g / (double)n);
  }
}

extern "C" void kernel_launch(void* const* d_in, const int* in_sizes, int n_in,
                              void* d_out, int out_size, void* d_ws, size_t ws_size,
                              hipStream_t stream) {
  const float* pred = (const float*)d_in[0];
  const float2* tg = (const float2*)d_in[1];
  float* out = (float*)d_out;
  const int n = in_sizes[0];  // 8192

  float4* ws_slots = (float4*)d_ws;

  svm_partial<<<dim3(GX, GY), BLK, 0, stream>>>(pred, tg, ws_slots);
  svm_finalize<<<1, 64, 0, stream>>>(ws_slots, out, n);
}